// Round 5
// baseline (470.931 us; speedup 1.0000x reference)
//
#include <hip/hip_runtime.h>

// Cross product along dim=1 of (16, 3, 1024, 1024) fp32 tensors.
// Layout (row-major): idx = ((b*3 + c)*1024 + h)*1024 + w.
//
// Measured r4: kernel=122.3us @ 3.29 TB/s (41% peak), FETCH 201MB (one input
// L3-resident), WRITE 201MB. Bench dur_us 442 = kernel 122 + ~320us harness
// fills. True HBM roofline for this dispatch ~64us; single-stream memset hits
// 82% of peak, we hit 41% -> theory: nine streams phase-locked at exact 4-MiB
// (power-of-2) offsets -> same DRAM channel/bank bits -> 9-deep same-bank
// bursts per thread.
//
// This revision: component-split de-phasing.
//  - block bid%3 computes only out_c (4 input planes, 1 output plane):
//    same-phase burst per thread drops 9 -> 4.
//  - each job's sweep shifted by c*OFFS (325KB, non-pow2-aligned bits) ->
//    the three jobs' streams hit different DRAM banks/channels at any instant.
//  - pair-unroll stride is 256 float4 = 4KB (not 4MiB) -> unrolled accesses
//    also de-phased.
//  - loads cacheable (cross-job re-reads, ~4MB window, served by L3);
//    stores stay nontemporal (never re-read).

typedef float vf4 __attribute__((ext_vector_type(4)));

#define P4   (1024 * 1024 / 4)   // 262144 float4 per component plane
#define NP   (16 * P4)           // 4,194,304 float4 positions (batch x plane)
#define OFFS 20800               // per-job phase shift in float4 units (=325KB)

__global__ __launch_bounds__(256) void cross_kernel(
    const vf4* __restrict__ in1,
    const vf4* __restrict__ in2,
    vf4* __restrict__ out)
{
    const int c     = blockIdx.x % 3;    // which output component this block owns
    const int chunk = blockIdx.x / 3;    // [0, 1024) contiguous 4096-float4 region
    const int p1    = (c + 1) % 3;       // out_c = in1[p1]*in2[p2] - in1[p2]*in2[p1]
    const int p2    = (c + 2) % 3;
    const int shift = c * OFFS;

    const int base_f = chunk * 4096 + (int)threadIdx.x;

    for (int it = 0; it < 16; it += 2) {
        int f1 = base_f + it * 256;
        int f2 = f1 + 256;
        int pos1 = f1 + shift; if (pos1 >= NP) pos1 -= NP;
        int pos2 = f2 + shift; if (pos2 >= NP) pos2 -= NP;

        // flat position -> (batch, r) -> float4 index of plane 0
        long r1 = (long)(pos1 >> 18) * (3 * P4) + (pos1 & (P4 - 1));
        long r2 = (long)(pos2 >> 18) * (3 * P4) + (pos2 & (P4 - 1));

        vf4 x1 = in1[r1 + p1 * P4];
        vf4 y1 = in2[r1 + p2 * P4];
        vf4 z1 = in1[r1 + p2 * P4];
        vf4 w1 = in2[r1 + p1 * P4];

        vf4 x2 = in1[r2 + p1 * P4];
        vf4 y2 = in2[r2 + p2 * P4];
        vf4 z2 = in1[r2 + p2 * P4];
        vf4 w2 = in2[r2 + p1 * P4];

        __builtin_nontemporal_store(x1 * y1 - z1 * w1, out + r1 + c * P4);
        __builtin_nontemporal_store(x2 * y2 - z2 * w2, out + r2 + c * P4);
    }
}

extern "C" void kernel_launch(void* const* d_in, const int* in_sizes, int n_in,
                              void* d_out, int out_size, void* d_ws, size_t ws_size,
                              hipStream_t stream) {
    const vf4* a = (const vf4*)d_in[0];
    const vf4* b = (const vf4*)d_in[1];
    vf4* out = (vf4*)d_out;

    // 3 jobs x 1024 chunks; each block: 256 threads x 16 float4 positions.
    // Covers 3 x NP work items exactly (NP = out_size/3/4 = 4,194,304).
    (void)out_size;
    int grid = 3 * 1024;
    cross_kernel<<<grid, 256, 0, stream>>>(a, b, out);
}

// Round 6
// 453.889 us; speedup vs baseline: 1.0375x; 1.0375x over previous
//
#include <hip/hip_runtime.h>

// Cross product along dim=1 of (16, 3, 1024, 1024) fp32 tensors.
// idx = ((b*3 + c)*1024 + h)*1024 + w; plane = 4MiB; batch = 3 planes.
//
// Measured: r4 (9-stream, nt, 12-deep MLP) kernel=122.3us, HBM 402MB @3.29TB/s,
// FETCH=201MB (50% of reads L3-resident across bench iterations).
// r5 (c-split, de-phased) = 188us @3.21TB/s, FETCH=402MB -> de-phasing changed
// nothing; duration ~ HBM_bytes/3.25. Fill=6.6TB/s (pure W), copy=6.29 (R~3.15).
// => read path saturates ~3.3TB/s; our 2:1 R:W op is read-limited.
//
// r6: r4 structure + deliberate L3 pinning to cut HBM reads:
//  - contiguous block mapping (block b owns positions [b*2048,(b+1)*2048)) so
//    cache policy can be block-uniform.
//  - in1 loads cacheable everywhere: 201MB fits in 256MB L3 -> pinned across
//    bench iterations.  in2 loads cacheable for first 448 blocks (+44MB,
//    total pinned 245MB <= 256), nontemporal elsewhere.  Stores nt (never
//    re-read; must not evict pins).
// Discriminates: FETCH 201->157MB with dur ~108us => HBM-bound (push further);
// FETCH drops but dur stays 122 => read-delivery roofline (declare); FETCH
// unchanged => L3 uncooperative, r4 structure is optimal.

typedef float vf4 __attribute__((ext_vector_type(4)));

#define P4 (1024 * 1024 / 4)   // float4 per component plane (262144)
#define PIN_BLOCKS 448          // in2-pinned prefix: 448*2048*16B = 14.7MB... (see launch: fraction of 2048 blocks)

__device__ __forceinline__ long plane_base(int i) {
    // i in [0, 16*P4): batch = i / P4, r = i % P4
    return (long)(i >> 18) * (3 * P4) + (i & (P4 - 1));
}

__global__ __launch_bounds__(256) void cross_kernel(
    const vf4* __restrict__ a,
    const vf4* __restrict__ b,
    vf4* __restrict__ out,
    int n4)
{
    const int base = blockIdx.x * 2048 + (int)threadIdx.x;
    const bool pin2 = (blockIdx.x < PIN_BLOCKS);   // block-uniform branch

    if (pin2) {
        #pragma unroll
        for (int k = 0; k < 8; k += 2) {
            const long p = plane_base(base + k * 256);
            const long q = plane_base(base + k * 256 + 256);
            vf4 a0 = a[p], a1 = a[p + P4], a2 = a[p + 2 * P4];
            vf4 b0 = b[p], b1 = b[p + P4], b2 = b[p + 2 * P4];
            vf4 a3 = a[q], a4 = a[q + P4], a5 = a[q + 2 * P4];
            vf4 b3 = b[q], b4 = b[q + P4], b5 = b[q + 2 * P4];
            __builtin_nontemporal_store(a1 * b2 - a2 * b1, out + p);
            __builtin_nontemporal_store(a2 * b0 - a0 * b2, out + p + P4);
            __builtin_nontemporal_store(a0 * b1 - a1 * b0, out + p + 2 * P4);
            __builtin_nontemporal_store(a4 * b5 - a5 * b4, out + q);
            __builtin_nontemporal_store(a5 * b3 - a3 * b5, out + q + P4);
            __builtin_nontemporal_store(a3 * b4 - a4 * b3, out + q + 2 * P4);
        }
    } else {
        #pragma unroll
        for (int k = 0; k < 8; k += 2) {
            const long p = plane_base(base + k * 256);
            const long q = plane_base(base + k * 256 + 256);
            // in1 cacheable (pinned); in2 nontemporal (don't evict pins)
            vf4 a0 = a[p], a1 = a[p + P4], a2 = a[p + 2 * P4];
            vf4 b0 = __builtin_nontemporal_load(b + p);
            vf4 b1 = __builtin_nontemporal_load(b + p + P4);
            vf4 b2 = __builtin_nontemporal_load(b + p + 2 * P4);
            vf4 a3 = a[q], a4 = a[q + P4], a5 = a[q + 2 * P4];
            vf4 b3 = __builtin_nontemporal_load(b + q);
            vf4 b4 = __builtin_nontemporal_load(b + q + P4);
            vf4 b5 = __builtin_nontemporal_load(b + q + 2 * P4);
            __builtin_nontemporal_store(a1 * b2 - a2 * b1, out + p);
            __builtin_nontemporal_store(a2 * b0 - a0 * b2, out + p + P4);
            __builtin_nontemporal_store(a0 * b1 - a1 * b0, out + p + 2 * P4);
            __builtin_nontemporal_store(a4 * b5 - a5 * b4, out + q);
            __builtin_nontemporal_store(a5 * b3 - a3 * b5, out + q + P4);
            __builtin_nontemporal_store(a3 * b4 - a4 * b3, out + q + 2 * P4);
        }
    }
}

extern "C" void kernel_launch(void* const* d_in, const int* in_sizes, int n_in,
                              void* d_out, int out_size, void* d_ws, size_t ws_size,
                              hipStream_t stream) {
    const vf4* a = (const vf4*)d_in[0];
    const vf4* b = (const vf4*)d_in[1];
    vf4* out = (vf4*)d_out;

    int n4 = out_size / 3 / 4;              // 4,194,304 float4 positions
    int grid = (n4 + 2047) / 2048;          // 2048 blocks, 2048 positions each
    cross_kernel<<<grid, 256, 0, stream>>>(a, b, out, n4);
}

// Round 9
// 438.637 us; speedup vs baseline: 1.0736x; 1.0348x over previous
//
#include <hip/hip_runtime.h>

// Cross product along dim=1 of (16, 3, 1024, 1024) fp32 tensors.
// idx = ((b*3 + c)*1024 + h)*1024 + w; plane = 4MiB; batch = 3 planes.
//
// Measured history:
//  r4 (grid-stride, all-nt, 12 loads in flight): 122.3us, FETCH 197MB,
//     WRITE 197MB, HBM-side 3.22 TB/s.  <-- best
//  r5 (c-split): HBM-side 3.19 TB/s; CU-side read delivery 4.28 TB/s
//     -> falsifies fixed read-path ceiling; points to outstanding-request
//        (latency x BW) limit.
//  r6 (contiguous chunks + mixed nt/cacheable): 165us REGRESSION; FETCH
//     unchanged -> L3 not steerable; contiguous mapping/cacheable loads hurt.
//
// r7: r4 exactly, but 4-position unroll: 24 nt loads (384B/thread) issued
// before first use -> 2x per-wave bytes in flight. launch_bounds(256,4)
// caps VGPR at 128 so resident waves stay ~16/CU (matches measured ~48%
// occupancy). Single-variable test of the MLP-limit theory.

typedef float vf4 __attribute__((ext_vector_type(4)));

#define P4 (1024 * 1024 / 4)   // float4 elements per component plane (262144, pow2)

#define NTL(p)    __builtin_nontemporal_load(p)
#define NTS(v, p) __builtin_nontemporal_store((v), (p))

__device__ __forceinline__ long plane_base(int i) {
    // i in [0, 16*P4): batch = i / P4, r = i % P4
    return (long)(i >> 18) * (3 * P4) + (i & (P4 - 1));
}

__global__ __launch_bounds__(256, 4) void cross_kernel(
    const vf4* __restrict__ a,
    const vf4* __restrict__ b,
    vf4* __restrict__ out,
    int n4)   // total float4 positions = 16 * P4 = 4,194,304
{
    const int nth = gridDim.x * blockDim.x;   // 524,288
    int i = blockIdx.x * blockDim.x + threadIdx.x;

    // 4-deep unrolled grid-stride loop: all 24 loads outstanding before any
    // use. n4 = 8*nth exactly -> 2 iterations, no tail (guards kept anyway).
    for (; i + 3 * nth < n4; i += 4 * nth) {
        long pp[4];
        vf4 A0[4], A1[4], A2[4], B0[4], B1[4], B2[4];
#pragma unroll
        for (int u = 0; u < 4; ++u) {
            pp[u] = plane_base(i + u * nth);
            A0[u] = NTL(a + pp[u]);
            A1[u] = NTL(a + pp[u] + P4);
            A2[u] = NTL(a + pp[u] + 2 * P4);
            B0[u] = NTL(b + pp[u]);
            B1[u] = NTL(b + pp[u] + P4);
            B2[u] = NTL(b + pp[u] + 2 * P4);
        }
#pragma unroll
        for (int u = 0; u < 4; ++u) {
            NTS(A1[u] * B2[u] - A2[u] * B1[u], out + pp[u]);
            NTS(A2[u] * B0[u] - A0[u] * B2[u], out + pp[u] + P4);
            NTS(A0[u] * B1[u] - A1[u] * B0[u], out + pp[u] + 2 * P4);
        }
    }

    // Tail (dead for this shape, kept for safety): one position at a time.
    for (; i < n4; i += nth) {
        const long p = plane_base(i);
        vf4 a0 = NTL(a + p), a1 = NTL(a + p + P4), a2 = NTL(a + p + 2 * P4);
        vf4 b0 = NTL(b + p), b1 = NTL(b + p + P4), b2 = NTL(b + p + 2 * P4);
        NTS(a1 * b2 - a2 * b1, out + p);
        NTS(a2 * b0 - a0 * b2, out + p + P4);
        NTS(a0 * b1 - a1 * b0, out + p + 2 * P4);
    }
}

extern "C" void kernel_launch(void* const* d_in, const int* in_sizes, int n_in,
                              void* d_out, int out_size, void* d_ws, size_t ws_size,
                              hipStream_t stream) {
    const vf4* a = (const vf4*)d_in[0];
    const vf4* b = (const vf4*)d_in[1];
    vf4* out = (vf4*)d_out;

    int n4 = out_size / 3 / 4;   // 4,194,304
    int block = 256;
    // 8 positions per thread -> 2048 blocks (8 blocks/CU), 2 quad-iterations.
    int grid = (n4 + block * 8 - 1) / (block * 8);
    cross_kernel<<<grid, block, 0, stream>>>(a, b, out, n4);
}